// Round 3
// baseline (2579.004 us; speedup 1.0000x reference)
//
#include <hip/hip_runtime.h>

#define DEV __device__ __forceinline__

typedef __attribute__((ext_vector_type(8))) short short8;
typedef __attribute__((ext_vector_type(4))) float floatx4;
typedef unsigned long long ull;

static constexpr int B_ = 512, T_ = 912, H_ = 128, F_ = 32;
static constexpr int RING = 64;                       // ring slots (8 chunks x 8)
static constexpr size_t HN_OFF   = 1024;              // bf16 hN[4][512][128]
static constexpr size_t XT_OFF   = HN_OFF + (size_t)4 * 512 * 128 * 2;
static constexpr size_t RING_OFF = XT_OFF + (size_t)T_ * B_ * F_ * 2;
// ring: [3 boundaries][32 groups][64 slots][16 b][128 k] bf16 -> qwords (8B)
static constexpr size_t RING_QW_PER_GRP = (size_t)RING * 16 * 128 / 4;   // 32768

DEV unsigned short bf16rne(float f) {
    unsigned u = __builtin_bit_cast(unsigned, f);
    u += 0x7FFFu + ((u >> 16) & 1u);
    return (unsigned short)(u >> 16);
}
DEV float bf16tof(unsigned short u) {
    return __builtin_bit_cast(float, ((unsigned)u) << 16);
}
DEV float sigm(float x) {
    return __builtin_amdgcn_rcpf(1.f + __builtin_amdgcn_exp2f(-1.44269504f * x));
}
DEV float tanh_(float x) {
    return 2.f * __builtin_amdgcn_rcpf(1.f + __builtin_amdgcn_exp2f(-2.88539008f * x)) - 1.f;
}

// ---------------------------------------------------------------------------
// x [B][T][32] fp32  ->  xT [T][B][32] bf16
__global__ __launch_bounds__(256) void xpose(const float* __restrict__ x,
                                             unsigned short* __restrict__ xT) {
    int tid = blockIdx.x * 256 + threadIdx.x;
    if (tid >= B_ * T_ * 4) return;
    int k = tid & 3;
    int r = tid >> 2;                                  // r = b*912 + t
    int b = r / T_;
    int t = r - b * T_;
    const float* p = x + ((size_t)r * 32 + k * 8);
    short8 v;
#pragma unroll
    for (int j = 0; j < 8; j++) v[j] = (short)bf16rne(p[j]);
    *(short8*)(xT + ((size_t)t * 512 + b) * 32 + k * 8) = v;
}

// ---------------------------------------------------------------------------
// Pipelined 4-layer LSTM scan, CHUNKED handoff (8 steps/chunk).
// 128 blocks = 4 layers x 32 groups (16 samples). Ah is a 16-deep LDS history
// ring; producer bursts 8 sc1 stores once per chunk (one ack drain per chunk),
// flag/cons/polls all once per chunk. LDS stride 132 shorts (2-way, free).
__global__ __launch_bounds__(512, 2) void lstm_scan(
    const float* __restrict__ Wih0, const float* __restrict__ Whh0,
    const float* __restrict__ bih0, const float* __restrict__ bhh0,
    const float* __restrict__ Wih123, const float* __restrict__ Whh123,
    const float* __restrict__ bih123, const float* __restrict__ bhh123,
    char* __restrict__ ws) {
    const int tid  = threadIdx.x;
    const int wv   = tid >> 6;     // 0..7
    const int lane = tid & 63;
    const int col  = lane & 15;
    const int quad = lane >> 4;
    const int blk  = blockIdx.x;
    const int layer = blk >> 5;
    const int grp   = blk & 31;
    const int b0    = grp * 16;

    unsigned* flags = (unsigned*)ws;                   // [4][32] producer chunks done
    unsigned* cons  = (unsigned*)(ws + 512);           // [4][32] consumer chunks read
    unsigned short* hN = (unsigned short*)(ws + HN_OFF);
    const unsigned short* xT = (const unsigned short*)(ws + XT_OFF);
    ull* ringAll = (ull*)(ws + RING_OFF);

    __shared__ unsigned short Ah[16][16][132];         // h history ring, stride 132
    __shared__ unsigned short Xl[2][16][132];          // staged prev-layer input

    for (int i = tid; i < 16 * 16 * 132; i += 512) ((unsigned short*)Ah)[i] = 0;

    // ---- persistent weight fragments (bf16) ------------------------------
    short8 wh[4][4];
    short8 wx[4][4];
    float  bias_q[4];
    const int KX = (layer == 0) ? 1 : 4;
    {
        const float *Wih, *Whh, *bih, *bhh;
        int kin;
        if (layer == 0) { Wih = Wih0; Whh = Whh0; bih = bih0; bhh = bhh0; kin = 32; }
        else {
            Wih = Wih123 + (size_t)(layer - 1) * 512 * 128;
            Whh = Whh123 + (size_t)(layer - 1) * 512 * 128;
            bih = bih123 + (size_t)(layer - 1) * 512;
            bhh = bhh123 + (size_t)(layer - 1) * 512;
            kin = 128;
        }
#pragma unroll
        for (int q = 0; q < 4; q++) {
            int row = q * 128 + wv * 16 + col;
            bias_q[q] = bih[row] + bhh[row];
#pragma unroll
            for (int kt = 0; kt < 4; kt++) {
                const float* ph = Whh + (size_t)row * 128 + kt * 32 + quad * 8;
                short8 v;
#pragma unroll
                for (int j = 0; j < 8; j++) v[j] = (short)bf16rne(ph[j]);
                wh[q][kt] = v;
            }
#pragma unroll
            for (int kt = 0; kt < 4; kt++) {
                short8 v = {0, 0, 0, 0, 0, 0, 0, 0};
                if (kt < KX) {
                    const float* px = Wih + (size_t)row * kin + kt * 32 + quad * 8;
#pragma unroll
                    for (int j = 0; j < 8; j++) v[j] = (short)bf16rne(px[j]);
                }
                wx[q][kt] = v;
            }
        }
    }

    unsigned* myflag   = &flags[layer * 32 + grp];
    unsigned* prevflag = &flags[(layer > 0 ? layer - 1 : 0) * 32 + grp];
    unsigned* mycons   = &cons[(layer > 0 ? layer - 1 : 0) * 32 + grp];
    unsigned* nextcons = &cons[layer * 32 + grp];
    ull* prodRing = ringAll + ((size_t)layer * 32 + grp) * RING_QW_PER_GRP;
    ull* consRing = ringAll + ((size_t)(layer > 0 ? layer - 1 : 0) * 32 + grp) * RING_QW_PER_GRP;

    const int cb = tid >> 5;       // staging row b (0..15)
    const int ck = tid & 31;       // qword within row

    ull dcur[8], dnext[8];
#pragma unroll
    for (int i = 0; i < 8; i++) { dcur[i] = 0; dnext[i] = 0; }

    // ---- prologue --------------------------------------------------------
    if (layer > 0) {
        if (tid == 0) {
            while (__hip_atomic_load(prevflag, __ATOMIC_RELAXED, __HIP_MEMORY_SCOPE_AGENT) < 2u) {}
        }
        __syncthreads();           // flag>=2: chunks 0,1 (steps 0..15) in ring
#pragma unroll
        for (int i = 0; i < 8; i++)
            dcur[i] = __hip_atomic_load(consRing + (size_t)i * 512 + cb * 32 + ck,
                                        __ATOMIC_RELAXED, __HIP_MEMORY_SCOPE_AGENT);
        *(ull*)&Xl[0][cb][ck * 4] = dcur[0];
    }
    short8 axc = {0, 0, 0, 0, 0, 0, 0, 0};
    if (layer == 0)
        axc = *(const short8*)(xT + ((size_t)0 * 512 + b0 + col) * 32 + quad * 8);
    __syncthreads();               // Ah zeros + Xl[0] visible

    float c4[4] = {0.f, 0.f, 0.f, 0.f};
    const int hcol = wv * 16 + col;

    for (int t = 0; t < T_; ++t) {
        const int j = t & 7;
        // ---- chunk-boundary work (j==0), amortized 8x --------------------
        unsigned pf = 0xffffffffu, pc = 0xffffffffu;
        if (j == 0) {
            if (tid == 0) {
                if (layer > 0)     // publish: chunks < t/8 fully read
                    __hip_atomic_store(mycons, (unsigned)(t >> 3), __ATOMIC_RELAXED,
                                       __HIP_MEMORY_SCOPE_AGENT);
                if (layer > 0 && t + 16 < T_)
                    pf = __hip_atomic_load(prevflag, __ATOMIC_RELAXED, __HIP_MEMORY_SCOPE_AGENT);
                if (layer < 3 && t >= 64)
                    pc = __hip_atomic_load(nextcons, __ATOMIC_RELAXED, __HIP_MEMORY_SCOPE_AGENT);
            }
            // producer burst: h[t-8..t-1] from Ah history -> ring (one drain)
            if (layer < 3 && t >= 8) {
#pragma unroll
                for (int i = 0; i < 8; i++) {
                    int s = t - 8 + i;
                    ull hv = *(const ull*)&Ah[s & 15][cb][ck * 4];
                    __hip_atomic_store(prodRing + (size_t)(s & (RING - 1)) * 512 + cb * 32 + ck,
                                       hv, __ATOMIC_RELAXED, __HIP_MEMORY_SCOPE_AGENT);
                }
            }
            // consumer burst: load chunk (t/8)+1 (flag >= t/8+2 verified last chunk)
            if (layer > 0 && t + 8 < T_) {
#pragma unroll
                for (int i = 0; i < 8; i++)
                    dnext[i] = __hip_atomic_load(consRing + (size_t)((t + 8 + i) & (RING - 1)) * 512
                                                 + cb * 32 + ck,
                                                 __ATOMIC_RELAXED, __HIP_MEMORY_SCOPE_AGENT);
            }
        }
        // layer0: x prefetch for t+1 (cached loads)
        short8 axn = {0, 0, 0, 0, 0, 0, 0, 0};
        if (layer == 0 && t + 1 < T_)
            axn = *(const short8*)(xT + ((size_t)(t + 1) * 512 + b0 + col) * 32 + quad * 8);

        // ---- A fragments (h[t-1] from history slot (t+15)&15) ------------
        short8 ah[4];
        {
            const unsigned short* base = &Ah[(t + 15) & 15][col][quad * 8];
#pragma unroll
            for (int kt = 0; kt < 4; kt++) ah[kt] = *(const short8*)(base + kt * 32);
        }
        short8 axf[4];
        if (layer > 0) {
            const unsigned short* base = &Xl[t & 1][col][quad * 8];
#pragma unroll
            for (int kt = 0; kt < 4; kt++) axf[kt] = *(const short8*)(base + kt * 32);
        }
        floatx4 acc[4];
#pragma unroll
        for (int q = 0; q < 4; q++) {
            float bq = bias_q[q];
            floatx4 a = {bq, bq, bq, bq};
            acc[q] = a;
        }
#pragma unroll
        for (int kt = 0; kt < 4; kt++)
#pragma unroll
            for (int q = 0; q < 4; q++)
                acc[q] = __builtin_amdgcn_mfma_f32_16x16x32_bf16(ah[kt], wh[q][kt], acc[q], 0, 0, 0);
        if (layer == 0) {
#pragma unroll
            for (int q = 0; q < 4; q++)
                acc[q] = __builtin_amdgcn_mfma_f32_16x16x32_bf16(axc, wx[q][0], acc[q], 0, 0, 0);
        } else {
#pragma unroll
            for (int kt = 0; kt < 4; kt++)
#pragma unroll
                for (int q = 0; q < 4; q++)
                    acc[q] = __builtin_amdgcn_mfma_f32_16x16x32_bf16(axf[kt], wx[q][kt], acc[q], 0, 0, 0);
        }
        // ---- gates + state update (mapping verified in R1/R2) ------------
#pragma unroll
        for (int r = 0; r < 4; r++) {
            float iv = sigm(acc[0][r]);
            float fv = sigm(acc[1][r]);
            float gv = tanh_(acc[2][r]);
            float ov = sigm(acc[3][r]);
            float cv = fv * c4[r] + iv * gv;
            c4[r] = cv;
            float hv = ov * tanh_(cv);
            unsigned short hb = bf16rne(hv);
            int m = quad * 4 + r;
            Ah[t & 15][m][hcol] = hb;
            if (t == T_ - 1)
                hN[((size_t)layer * 512 + b0 + m) * 128 + hcol] = hb;
        }
        // ---- stage next step's input from chunk registers ----------------
        if (layer > 0 && t + 1 < T_) {
            ull stage = (j < 7) ? dcur[j + 1] : dnext[0];
            *(ull*)&Xl[1 - (t & 1)][cb][ck * 4] = stage;
        }
        if (j == 7) {
#pragma unroll
            for (int i = 0; i < 8; i++) dcur[i] = dnext[i];
        }
        // ---- chunk-end spin-verify (poll issued 7 steps earlier) ---------
        if (j == 7 && tid == 0) {
            if (layer > 0 && t + 16 < T_) {             // for chunk issue at t+1..
                unsigned tgt = (unsigned)((t >> 3) + 3);
                if (pf < tgt)
                    while (__hip_atomic_load(prevflag, __ATOMIC_RELAXED, __HIP_MEMORY_SCOPE_AGENT) < tgt) {}
            }
            if (layer < 3 && t >= 71) {                 // ring overwrite guard
                unsigned tgt = (unsigned)(((t + 1) >> 3) - 8);
                if (pc < tgt)
                    while (__hip_atomic_load(nextcons, __ATOMIC_RELAXED, __HIP_MEMORY_SCOPE_AGENT) < tgt) {}
            }
        }
        __syncthreads();           // drains vmcnt(0): burst stores acked at chunk steps
        if (tid == 0 && layer < 3 && t >= 8 && j == 0)
            __hip_atomic_store(myflag, (unsigned)(t >> 3), __ATOMIC_RELAXED,
                               __HIP_MEMORY_SCOPE_AGENT);
        if (layer == 0) axc = axn;
    }
    // ---- epilogue: burst chunk 113 (h[904..911]), publish final ----------
    if (layer < 3) {
#pragma unroll
        for (int i = 0; i < 8; i++) {
            int s = 904 + i;
            ull hv = *(const ull*)&Ah[s & 15][cb][ck * 4];
            __hip_atomic_store(prodRing + (size_t)(s & (RING - 1)) * 512 + cb * 32 + ck,
                               hv, __ATOMIC_RELAXED, __HIP_MEMORY_SCOPE_AGENT);
        }
        __syncthreads();           // vmcnt(0) drain
        if (tid == 0)
            __hip_atomic_store(myflag, 200u, __ATOMIC_RELAXED, __HIP_MEMORY_SCOPE_AGENT);
    }
}

// ---------------------------------------------------------------------------
// heads: hN [4][512][128] bf16 -> opt/tp/sl/lot, each [4][512][4] fp32
__global__ __launch_bounds__(256) void heads(
    const unsigned short* __restrict__ hN,
    const float* __restrict__ Wopt, const float* __restrict__ bopt,
    const float* __restrict__ Wlot, const float* __restrict__ blot,
    const float* __restrict__ Wtp,  const float* __restrict__ btp,
    const float* __restrict__ Wsl,  const float* __restrict__ bsl,
    float* __restrict__ out) {
    int tid = blockIdx.x * 256 + threadIdx.x;
    if (tid >= 4 * 4 * 512) return;
    int b  = tid & 511;
    int l  = (tid >> 9) & 3;
    int hd = tid >> 11;
    const float *W, *bb;
    if      (hd == 0) { W = Wopt; bb = bopt; }
    else if (hd == 1) { W = Wtp;  bb = btp;  }
    else if (hd == 2) { W = Wsl;  bb = bsl;  }
    else              { W = Wlot; bb = blot; }
    const unsigned short* h = hN + ((size_t)l * 512 + b) * 128;
    float z0 = bb[0], z1 = bb[1], z2 = bb[2], z3 = bb[3];
    for (int i = 0; i < 128; i++) {
        float hv = bf16tof(h[i]);
        z0 += hv * W[0 * 128 + i];
        z1 += hv * W[1 * 128 + i];
        z2 += hv * W[2 * 128 + i];
        z3 += hv * W[3 * 128 + i];
    }
    float o0, o1, o2, o3;
    if (hd == 0) {
        float m = fmaxf(fmaxf(z0, z1), fmaxf(z2, z3));
        float e0 = __builtin_amdgcn_exp2f((z0 - m) * 1.44269504f);
        float e1 = __builtin_amdgcn_exp2f((z1 - m) * 1.44269504f);
        float e2 = __builtin_amdgcn_exp2f((z2 - m) * 1.44269504f);
        float e3 = __builtin_amdgcn_exp2f((z3 - m) * 1.44269504f);
        float rs = __builtin_amdgcn_rcpf(e0 + e1 + e2 + e3);
        float p0 = e0 * rs, p1 = e1 * rs, p2 = e2 * rs, p3 = e3 * rs;
        float m2 = fmaxf(fmaxf(p0, p1), fmaxf(p2, p3));
        float f0 = __builtin_amdgcn_exp2f((p0 - m2) * 1.44269504f);
        float f1 = __builtin_amdgcn_exp2f((p1 - m2) * 1.44269504f);
        float f2 = __builtin_amdgcn_exp2f((p2 - m2) * 1.44269504f);
        float f3 = __builtin_amdgcn_exp2f((p3 - m2) * 1.44269504f);
        float rs2 = __builtin_amdgcn_rcpf(f0 + f1 + f2 + f3);
        o0 = f0 * rs2; o1 = f1 * rs2; o2 = f2 * rs2; o3 = f3 * rs2;
    } else {
        o0 = sigm(sigm(z0)); o1 = sigm(sigm(z1));
        o2 = sigm(sigm(z2)); o3 = sigm(sigm(z3));
    }
    float* o = out + (size_t)hd * 8192 + ((size_t)l * 512 + b) * 4;
    o[0] = o0; o[1] = o1; o[2] = o2; o[3] = o3;
}

// ---------------------------------------------------------------------------
extern "C" void kernel_launch(void* const* d_in, const int* in_sizes, int n_in,
                              void* d_out, int out_size, void* d_ws, size_t ws_size,
                              hipStream_t stream) {
    (void)in_sizes; (void)n_in; (void)out_size; (void)ws_size;
    const float* x      = (const float*)d_in[0];
    const float* Wih0   = (const float*)d_in[1];
    const float* Whh0   = (const float*)d_in[2];
    const float* bih0   = (const float*)d_in[3];
    const float* bhh0   = (const float*)d_in[4];
    const float* Wih123 = (const float*)d_in[5];
    const float* Whh123 = (const float*)d_in[6];
    const float* bih123 = (const float*)d_in[7];
    const float* bhh123 = (const float*)d_in[8];
    const float* Wopt = (const float*)d_in[9];
    const float* bopt = (const float*)d_in[10];
    const float* Wlot = (const float*)d_in[11];
    const float* blot = (const float*)d_in[12];
    const float* Wtp  = (const float*)d_in[13];
    const float* btp  = (const float*)d_in[14];
    const float* Wsl  = (const float*)d_in[15];
    const float* bsl  = (const float*)d_in[16];
    char* ws = (char*)d_ws;

    hipMemsetAsync(ws, 0, 1024, stream);               // flags + cons
    xpose<<<(B_ * T_ * 4 + 255) / 256, 256, 0, stream>>>(x, (unsigned short*)(ws + XT_OFF));
    lstm_scan<<<128, 512, 0, stream>>>(Wih0, Whh0, bih0, bhh0,
                                       Wih123, Whh123, bih123, bhh123, ws);
    heads<<<32, 256, 0, stream>>>((const unsigned short*)(ws + HN_OFF),
                                  Wopt, bopt, Wlot, blot, Wtp, btp, Wsl, bsl,
                                  (float*)d_out);
}

// Round 4
// 2323.695 us; speedup vs baseline: 1.1099x; 1.1099x over previous
//
#include <hip/hip_runtime.h>

#define DEV __device__ __forceinline__

typedef __attribute__((ext_vector_type(8))) short short8;
typedef __attribute__((ext_vector_type(4))) float floatx4;
typedef unsigned long long ull;

static constexpr int B_ = 512, T_ = 912, H_ = 128, F_ = 32;
static constexpr size_t HN_OFF   = 1024;                       // bf16 hN[4][512][128]
static constexpr size_t XT_OFF   = HN_OFF + (size_t)4 * 512 * 128 * 2;   // 525312
static constexpr size_t RING_OFF = XT_OFF + (size_t)T_ * B_ * F_ * 2;    // 30409728
// ring per boundary-group: 8 regions x 32KB ([slot][16 rows][256B])
static constexpr size_t RING_BPG = 8 * 32768;                  // 256 KB

template <int N> struct IC { static constexpr int value = N; };

DEV unsigned short bf16rne(float f) {
    unsigned u = __builtin_bit_cast(unsigned, f);
    u += 0x7FFFu + ((u >> 16) & 1u);
    return (unsigned short)(u >> 16);
}
DEV float bf16tof(unsigned short u) {
    return __builtin_bit_cast(float, ((unsigned)u) << 16);
}
DEV float fastsig(float y) {     // rcp(1+exp2(y))
    return __builtin_amdgcn_rcpf(1.f + __builtin_amdgcn_exp2f(y));
}
DEV float sigm(float x) { return fastsig(-1.44269504f * x); }
DEV unsigned ald(const unsigned* p) {
    return __hip_atomic_load(p, __ATOMIC_RELAXED, __HIP_MEMORY_SCOPE_AGENT);
}
DEV void ast32(unsigned* p, unsigned v) {
    __hip_atomic_store(p, v, __ATOMIC_RELAXED, __HIP_MEMORY_SCOPE_AGENT);
}
DEV ull ald8(const ull* p) {
    return __hip_atomic_load(p, __ATOMIC_RELAXED, __HIP_MEMORY_SCOPE_AGENT);
}
DEV void ast8(ull* p, ull v) {
    __hip_atomic_store(p, v, __ATOMIC_RELAXED, __HIP_MEMORY_SCOPE_AGENT);
}
DEV void bar_fast() {            // LDS-only barrier: no vmcnt drain
    asm volatile("s_waitcnt lgkmcnt(0)\n\ts_barrier" ::: "memory");
}

// ---------------------------------------------------------------------------
// x [B][T][32] fp32  ->  xT [T][B][32] bf16
__global__ __launch_bounds__(256) void xpose(const float* __restrict__ x,
                                             unsigned short* __restrict__ xT) {
    int tid = blockIdx.x * 256 + threadIdx.x;
    if (tid >= B_ * T_ * 4) return;
    int k = tid & 3;
    int r = tid >> 2;                                  // r = b*912 + t
    int b = r / T_;
    int t = r - b * T_;
    const float* p = x + ((size_t)r * 32 + k * 8);
    short8 v;
#pragma unroll
    for (int j = 0; j < 8; j++) v[j] = (short)bf16rne(p[j]);
    *(short8*)(xT + ((size_t)t * 512 + b) * 32 + k * 8) = v;
}

// ---------------------------------------------------------------------------
// Pipelined 4-layer LSTM scan. 128 blocks = 4 layers x 32 groups (16 samples).
// t-loop unrolled x16: all LDS offsets are immediates. lgkm-only barriers on
// 14/16 steps; one full __syncthreads per chunk (u==3/11) = release point.
// Activation scales folded into weights. Chunked MALL ring handoff (8 steps).
__global__ __launch_bounds__(512, 2) void lstm_scan(
    const float* __restrict__ Wih0, const float* __restrict__ Whh0,
    const float* __restrict__ bih0, const float* __restrict__ bhh0,
    const float* __restrict__ Wih123, const float* __restrict__ Whh123,
    const float* __restrict__ bih123, const float* __restrict__ bhh123,
    char* __restrict__ ws) {
    const int tid  = threadIdx.x;
    const int wv   = tid >> 6;
    const int lane = tid & 63;
    const int col  = lane & 15;
    const int quad = lane >> 4;
    const int layer = blockIdx.x >> 5;
    const int grp   = blockIdx.x & 31;
    const int b0    = grp * 16;

    unsigned* flags = (unsigned*)ws;                   // [4][32] chunks published
    unsigned* cons  = (unsigned*)(ws + 512);           // [4][32] chunks loaded
    char* hN8 = ws + HN_OFF;
    const char* xTB = ws + XT_OFF;

    __shared__ unsigned short Ah[16][16][132];         // h history ring (slot = t&15)
    __shared__ unsigned short Xl[16][16][132];         // staged input (slot = t&15)
    char* AhB = (char*)Ah;
    char* XlB = (char*)Xl;

    for (int i = tid; i < 16 * 16 * 132; i += 512) {
        ((unsigned short*)Ah)[i] = 0;
        ((unsigned short*)Xl)[i] = 0;
    }

    // ---- persistent weights, activation scale folded in ------------------
    short8 wh[4][4];
    short8 wx[4][4];
    float  bias_q[4];
    {
        const float *Wih, *Whh, *bih, *bhh;
        int kin, KX;
        if (layer == 0) { Wih = Wih0; Whh = Whh0; bih = bih0; bhh = bhh0; kin = 32; KX = 1; }
        else {
            Wih = Wih123 + (size_t)(layer - 1) * 512 * 128;
            Whh = Whh123 + (size_t)(layer - 1) * 512 * 128;
            bih = bih123 + (size_t)(layer - 1) * 512;
            bhh = bhh123 + (size_t)(layer - 1) * 512;
            kin = 128; KX = 4;
        }
#pragma unroll
        for (int q = 0; q < 4; q++) {
            const float sc = (q == 2) ? -2.88539008f : -1.44269504f;
            int row = q * 128 + wv * 16 + col;
            bias_q[q] = (bih[row] + bhh[row]) * sc;
#pragma unroll
            for (int kt = 0; kt < 4; kt++) {
                const float* ph = Whh + (size_t)row * 128 + kt * 32 + quad * 8;
                short8 v;
#pragma unroll
                for (int j = 0; j < 8; j++) v[j] = (short)bf16rne(ph[j] * sc);
                wh[q][kt] = v;
            }
#pragma unroll
            for (int kt = 0; kt < 4; kt++) {
                short8 v = {0, 0, 0, 0, 0, 0, 0, 0};
                if (kt < KX) {
                    const float* px = Wih + (size_t)row * kin + kt * 32 + quad * 8;
#pragma unroll
                    for (int j = 0; j < 8; j++) v[j] = (short)bf16rne(px[j] * sc);
                }
                wx[q][kt] = v;
            }
        }
    }

    unsigned* myflag   = &flags[layer * 32 + grp];
    unsigned* prevflag = &flags[(layer > 0 ? layer - 1 : 0) * 32 + grp];
    unsigned* mycons   = &cons[(layer > 0 ? layer - 1 : 0) * 32 + grp];
    unsigned* nextcons = &cons[layer * 32 + grp];
    char* prodRing = ws + RING_OFF + (size_t)(layer * 32 + grp) * RING_BPG;
    char* consRing = ws + RING_OFF + (size_t)((layer > 0 ? layer - 1 : 0) * 32 + grp) * RING_BPG;

    // precomputed byte offsets (constants through the whole kernel)
    const int ahrd  = col * 264 + quad * 16;                    // A-frag base
    const int hwr   = (quad * 4) * 264 + (wv * 16 + col) * 2;   // h write base
    const int exOff = (tid >> 5) * 264 + (tid & 31) * 8;        // export/stage base
    const int consOff = (tid >> 5) * 256 + (tid & 31) * 8;      // ring qword offset
    const int xgOff = (tid >> 6) * 32768 + b0 * 64 + (tid & 63) * 16;   // xT chunk
    const int xlw0  = (tid >> 6) * 4224 + ((tid >> 2) & 15) * 264 + (tid & 3) * 16;

    ull    xin[8];
    short8 xv = {0, 0, 0, 0, 0, 0, 0, 0};
    unsigned pf = 0, pc = 0;
    float c4[4] = {0.f, 0.f, 0.f, 0.f};

    __syncthreads();                                   // LDS zeros visible

    // ---- prologue: load+stage chunks 0,1 ---------------------------------
    if (layer > 0) {
        if (tid == 0) { while (ald(prevflag) < 2u) {} }
        __syncthreads();
#pragma unroll
        for (int j = 0; j < 16; j++) {
            ull d = ald8((const ull*)(consRing + (size_t)j * 4096 + consOff));
            *(ull*)(XlB + exOff + j * 4224) = d;
        }
    } else {
#pragma unroll
        for (int c0 = 0; c0 < 2; c0++) {
            short8 v = *(const short8*)(xTB + (size_t)c0 * 262144 + xgOff);
            *(short8*)(XlB + xlw0 + c0 * 33792) = v;
        }
    }
    __syncthreads();

    int c = 0;
    auto step = [&](auto UC) {
        constexpr int u   = UC.value;
        constexpr bool bnd = (u == 0 || u == 8);
        constexpr bool stg = (u == 3 || u == 11);
        constexpr bool ver = (u == 7 || u == 15);
        constexpr int sph = (u < 8) ? 8 : 0;           // slot base for export/stage
        const int cc = c + (u >> 3);
        if (bnd) {
            if (tid == 0) {
                if (layer > 0 && cc <= 111) pf = ald(prevflag);
                if (layer < 3 && cc >= 8)   pc = ald(nextcons);
            }
            if (layer < 3 && cc >= 1) {                // burst chunk cc-1 -> ring
                char* rb = prodRing + (size_t)((cc - 1) & 7) * 32768 + tid * 8;
#pragma unroll
                for (int p = 0; p < 8; p++) {
                    ull hv = *(const ull*)(AhB + exOff + (sph + p) * 4224);
                    ast8((ull*)(rb + p * 4096), hv);
                }
            }
            if (layer > 0 && cc <= 112) {              // load chunk cc+1
                const char* rb2 = consRing + (size_t)((cc + 1) & 7) * 32768 + consOff;
#pragma unroll
                for (int j = 0; j < 8; j++)
                    xin[j] = ald8((const ull*)(rb2 + j * 4096));
            }
            if (layer == 0 && cc <= 112)
                xv = *(const short8*)(xTB + (size_t)(cc + 1) * 262144 + xgOff);
        }
        if (stg) {                                     // stage chunk cc+1 into Xl
            if (layer > 0) {
#pragma unroll
                for (int j = 0; j < 8; j++)
                    *(ull*)(XlB + exOff + (sph + j) * 4224) = xin[j];
            } else {
                *(short8*)(XlB + xlw0 + sph * 4224) = xv;
            }
        }
        // ---- A fragments (all offsets are immediates) --------------------
        short8 ah[4], ax[4];
#pragma unroll
        for (int kt = 0; kt < 4; kt++) {
            ah[kt] = *(const short8*)(AhB + ahrd + ((u + 15) & 15) * 4224 + kt * 64);
            ax[kt] = *(const short8*)(XlB + ahrd + u * 4224 + kt * 64);
        }
        floatx4 acc[4];
#pragma unroll
        for (int q = 0; q < 4; q++) {
            floatx4 a = {bias_q[q], bias_q[q], bias_q[q], bias_q[q]};
            acc[q] = a;
        }
#pragma unroll
        for (int kt = 0; kt < 4; kt++)
#pragma unroll
            for (int q = 0; q < 4; q++)
                acc[q] = __builtin_amdgcn_mfma_f32_16x16x32_bf16(ah[kt], wh[q][kt], acc[q], 0, 0, 0);
#pragma unroll
        for (int kt = 0; kt < 4; kt++)
#pragma unroll
            for (int q = 0; q < 4; q++)
                acc[q] = __builtin_amdgcn_mfma_f32_16x16x32_bf16(ax[kt], wx[q][kt], acc[q], 0, 0, 0);
        // ---- gates (scales pre-folded: z' = -1.4427z / -2.8854z) ---------
#pragma unroll
        for (int r = 0; r < 4; r++) {
            float iv = fastsig(acc[0][r]);
            float fv = fastsig(acc[1][r]);
            float gr = fastsig(acc[2][r]);             // (tanh(g)+1)/2
            float ov = fastsig(acc[3][r]);
            float gt = 2.f * gr - 1.f;
            float cv = fv * c4[r] + iv * gt;
            c4[r] = cv;
            float rc = fastsig(-2.88539008f * cv);
            float hv = ov * (2.f * rc - 1.f);
            *(unsigned short*)(AhB + hwr + u * 4224 + r * 264) = bf16rne(hv);
        }
        if (stg) {
            __syncthreads();                           // full drain: release point
            if (tid == 0) {
                if (layer < 3 && cc >= 1) ast32(myflag, (unsigned)cc);
                if (layer > 0) ast32(mycons, (unsigned)(cc + 2));
            }
        } else {
            if (ver && tid == 0) {
                if (layer > 0 && cc <= 111) {
                    unsigned tgt = cc + 3;
                    if (pf < tgt) while (ald(prevflag) < tgt) {}
                }
                if (layer < 3 && cc >= 8) {
                    unsigned tgt = cc - 7;
                    if (pc < tgt) while (ald(nextcons) < tgt) {}
                }
            }
            bar_fast();
        }
    };

    for (c = 0; c < 114; c += 2) {
        step(IC<0>{});  step(IC<1>{});  step(IC<2>{});  step(IC<3>{});
        step(IC<4>{});  step(IC<5>{});  step(IC<6>{});  step(IC<7>{});
        step(IC<8>{});  step(IC<9>{});  step(IC<10>{}); step(IC<11>{});
        step(IC<12>{}); step(IC<13>{}); step(IC<14>{}); step(IC<15>{});
    }

    // ---- epilogue: burst chunk 113 (slots 8..15), publish, export hN -----
    if (layer < 3) {
        char* rb = prodRing + (size_t)(113 & 7) * 32768 + tid * 8;
#pragma unroll
        for (int p = 0; p < 8; p++) {
            ull hv = *(const ull*)(AhB + exOff + (8 + p) * 4224);
            ast8((ull*)(rb + p * 4096), hv);
        }
    }
    __syncthreads();                                   // drain ring stores
    if (tid == 0 && layer < 3) ast32(myflag, 114u);
    {
        ull hv = *(const ull*)(AhB + exOff + 15 * 4224);   // h[911]
        *(ull*)(hN8 + ((size_t)layer * 512 + b0 + (tid >> 5)) * 256 + (tid & 31) * 8) = hv;
    }
}

// ---------------------------------------------------------------------------
// heads: hN [4][512][128] bf16 -> opt/tp/sl/lot, each [4][512][4] fp32
__global__ __launch_bounds__(256) void heads(
    const unsigned short* __restrict__ hN,
    const float* __restrict__ Wopt, const float* __restrict__ bopt,
    const float* __restrict__ Wlot, const float* __restrict__ blot,
    const float* __restrict__ Wtp,  const float* __restrict__ btp,
    const float* __restrict__ Wsl,  const float* __restrict__ bsl,
    float* __restrict__ out) {
    int tid = blockIdx.x * 256 + threadIdx.x;
    if (tid >= 4 * 4 * 512) return;
    int b  = tid & 511;
    int l  = (tid >> 9) & 3;
    int hd = tid >> 11;
    const float *W, *bb;
    if      (hd == 0) { W = Wopt; bb = bopt; }
    else if (hd == 1) { W = Wtp;  bb = btp;  }
    else if (hd == 2) { W = Wsl;  bb = bsl;  }
    else              { W = Wlot; bb = blot; }
    const unsigned short* h = hN + ((size_t)l * 512 + b) * 128;
    float z0 = bb[0], z1 = bb[1], z2 = bb[2], z3 = bb[3];
    for (int i = 0; i < 128; i++) {
        float hv = bf16tof(h[i]);
        z0 += hv * W[0 * 128 + i];
        z1 += hv * W[1 * 128 + i];
        z2 += hv * W[2 * 128 + i];
        z3 += hv * W[3 * 128 + i];
    }
    float o0, o1, o2, o3;
    if (hd == 0) {
        float m = fmaxf(fmaxf(z0, z1), fmaxf(z2, z3));
        float e0 = __builtin_amdgcn_exp2f((z0 - m) * 1.44269504f);
        float e1 = __builtin_amdgcn_exp2f((z1 - m) * 1.44269504f);
        float e2 = __builtin_amdgcn_exp2f((z2 - m) * 1.44269504f);
        float e3 = __builtin_amdgcn_exp2f((z3 - m) * 1.44269504f);
        float rs = __builtin_amdgcn_rcpf(e0 + e1 + e2 + e3);
        float p0 = e0 * rs, p1 = e1 * rs, p2 = e2 * rs, p3 = e3 * rs;
        float m2 = fmaxf(fmaxf(p0, p1), fmaxf(p2, p3));
        float f0 = __builtin_amdgcn_exp2f((p0 - m2) * 1.44269504f);
        float f1 = __builtin_amdgcn_exp2f((p1 - m2) * 1.44269504f);
        float f2 = __builtin_amdgcn_exp2f((p2 - m2) * 1.44269504f);
        float f3 = __builtin_amdgcn_exp2f((p3 - m2) * 1.44269504f);
        float rs2 = __builtin_amdgcn_rcpf(f0 + f1 + f2 + f3);
        o0 = f0 * rs2; o1 = f1 * rs2; o2 = f2 * rs2; o3 = f3 * rs2;
    } else {
        o0 = sigm(sigm(z0)); o1 = sigm(sigm(z1));
        o2 = sigm(sigm(z2)); o3 = sigm(sigm(z3));
    }
    float* o = out + (size_t)hd * 8192 + ((size_t)l * 512 + b) * 4;
    o[0] = o0; o[1] = o1; o[2] = o2; o[3] = o3;
}

// ---------------------------------------------------------------------------
extern "C" void kernel_launch(void* const* d_in, const int* in_sizes, int n_in,
                              void* d_out, int out_size, void* d_ws, size_t ws_size,
                              hipStream_t stream) {
    (void)in_sizes; (void)n_in; (void)out_size; (void)ws_size;
    const float* x      = (const float*)d_in[0];
    const float* Wih0   = (const float*)d_in[1];
    const float* Whh0   = (const float*)d_in[2];
    const float* bih0   = (const float*)d_in[3];
    const float* bhh0   = (const float*)d_in[4];
    const float* Wih123 = (const float*)d_in[5];
    const float* Whh123 = (const float*)d_in[6];
    const float* bih123 = (const float*)d_in[7];
    const float* bhh123 = (const float*)d_in[8];
    const float* Wopt = (const float*)d_in[9];
    const float* bopt = (const float*)d_in[10];
    const float* Wlot = (const float*)d_in[11];
    const float* blot = (const float*)d_in[12];
    const float* Wtp  = (const float*)d_in[13];
    const float* btp  = (const float*)d_in[14];
    const float* Wsl  = (const float*)d_in[15];
    const float* bsl  = (const float*)d_in[16];
    char* ws = (char*)d_ws;

    hipMemsetAsync(ws, 0, 1024, stream);               // flags + cons
    xpose<<<(B_ * T_ * 4 + 255) / 256, 256, 0, stream>>>(x, (unsigned short*)(ws + XT_OFF));
    lstm_scan<<<128, 512, 0, stream>>>(Wih0, Whh0, bih0, bhh0,
                                       Wih123, Whh123, bih123, bhh123, ws);
    heads<<<32, 256, 0, stream>>>((const unsigned short*)(ws + HN_OFF),
                                  Wopt, bopt, Wlot, blot, Wtp, btp, Wsl, bsl,
                                  (float*)d_out);
}

// Round 5
// 2120.645 us; speedup vs baseline: 1.2161x; 1.0957x over previous
//
#include <hip/hip_runtime.h>

#define DEV __device__ __forceinline__

typedef __attribute__((ext_vector_type(8))) short short8;
typedef __attribute__((ext_vector_type(4))) float floatx4;
typedef unsigned long long ull;

static constexpr int B_ = 512, T_ = 912, H_ = 128, F_ = 32;
static constexpr size_t HN_OFF   = 1024;                       // bf16 hN[4][512][128]
static constexpr size_t XT_OFF   = HN_OFF + (size_t)4 * 512 * 128 * 2;   // 525312
static constexpr size_t RING_OFF = XT_OFF + (size_t)T_ * B_ * F_ * 2;    // 30409728
// ring per boundary-group: 8 regions x 32KB ([slot][16 rows][256B])
static constexpr size_t RING_BPG = 8 * 32768;                  // 256 KB

template <int N> struct IC { static constexpr int value = N; };

DEV unsigned short bf16rne(float f) {
    unsigned u = __builtin_bit_cast(unsigned, f);
    u += 0x7FFFu + ((u >> 16) & 1u);
    return (unsigned short)(u >> 16);
}
DEV float bf16tof(unsigned short u) {
    return __builtin_bit_cast(float, ((unsigned)u) << 16);
}
DEV float fastsig(float y) {     // rcp(1+exp2(y))
    return __builtin_amdgcn_rcpf(1.f + __builtin_amdgcn_exp2f(y));
}
DEV float sigm(float x) { return fastsig(-1.44269504f * x); }
DEV unsigned ald(const unsigned* p) {
    return __hip_atomic_load(p, __ATOMIC_RELAXED, __HIP_MEMORY_SCOPE_AGENT);
}
DEV void ast32(unsigned* p, unsigned v) {
    __hip_atomic_store(p, v, __ATOMIC_RELAXED, __HIP_MEMORY_SCOPE_AGENT);
}
DEV ull ald8(const ull* p) {
    return __hip_atomic_load(p, __ATOMIC_RELAXED, __HIP_MEMORY_SCOPE_AGENT);
}
DEV void ast8(ull* p, ull v) {
    __hip_atomic_store(p, v, __ATOMIC_RELAXED, __HIP_MEMORY_SCOPE_AGENT);
}
DEV void bar_fast() {            // LDS-only barrier: no vmcnt drain
    asm volatile("s_waitcnt lgkmcnt(0)\n\ts_barrier" ::: "memory");
}

// ---------------------------------------------------------------------------
// x [B][T][32] fp32  ->  xT [T][B][32] bf16
__global__ __launch_bounds__(256) void xpose(const float* __restrict__ x,
                                             unsigned short* __restrict__ xT) {
    int tid = blockIdx.x * 256 + threadIdx.x;
    if (tid >= B_ * T_ * 4) return;
    int k = tid & 3;
    int r = tid >> 2;                                  // r = b*912 + t
    int b = r / T_;
    int t = r - b * T_;
    const float* p = x + ((size_t)r * 32 + k * 8);
    short8 v;
#pragma unroll
    for (int j = 0; j < 8; j++) v[j] = (short)bf16rne(p[j]);
    *(short8*)(xT + ((size_t)t * 512 + b) * 32 + k * 8) = v;
}

// ---------------------------------------------------------------------------
// Pipelined 4-layer LSTM scan. 128 blocks = 4 layers x 32 groups (16 samples).
// SOFTWARE-PIPELINED step: x-part MFMAs of step t+1 (ring data, no recurrence
// dep) are interleaved with step t's gate/trans chain so MFMA + trans + LDS
// pipes overlap instead of running in barrier-locked phases.
__global__ __launch_bounds__(512, 2) void lstm_scan(
    const float* __restrict__ Wih0, const float* __restrict__ Whh0,
    const float* __restrict__ bih0, const float* __restrict__ bhh0,
    const float* __restrict__ Wih123, const float* __restrict__ Whh123,
    const float* __restrict__ bih123, const float* __restrict__ bhh123,
    char* __restrict__ ws) {
    const int tid  = threadIdx.x;
    const int wv   = tid >> 6;
    const int lane = tid & 63;
    const int col  = lane & 15;
    const int quad = lane >> 4;
    const int layer = blockIdx.x >> 5;
    const int grp   = blockIdx.x & 31;
    const int b0    = grp * 16;

    unsigned* flags = (unsigned*)ws;                   // [4][32] chunks published
    unsigned* cons  = (unsigned*)(ws + 512);           // [4][32] chunks loaded
    char* hN8 = ws + HN_OFF;
    const char* xTB = ws + XT_OFF;

    __shared__ unsigned short Ah[16][16][132];         // h history ring (slot = t&15)
    __shared__ unsigned short Xl[16][16][132];         // staged input (slot = t&15)
    char* AhB = (char*)Ah;
    char* XlB = (char*)Xl;

    for (int i = tid; i < 16 * 16 * 132; i += 512) {
        ((unsigned short*)Ah)[i] = 0;
        ((unsigned short*)Xl)[i] = 0;
    }

    // ---- persistent weights, activation scale folded in ------------------
    short8 wh[4][4];
    short8 wx[4][4];
    float  bias_q[4];
    {
        const float *Wih, *Whh, *bih, *bhh;
        int kin, KX;
        if (layer == 0) { Wih = Wih0; Whh = Whh0; bih = bih0; bhh = bhh0; kin = 32; KX = 1; }
        else {
            Wih = Wih123 + (size_t)(layer - 1) * 512 * 128;
            Whh = Whh123 + (size_t)(layer - 1) * 512 * 128;
            bih = bih123 + (size_t)(layer - 1) * 512;
            bhh = bhh123 + (size_t)(layer - 1) * 512;
            kin = 128; KX = 4;
        }
#pragma unroll
        for (int q = 0; q < 4; q++) {
            const float sc = (q == 2) ? -2.88539008f : -1.44269504f;
            int row = q * 128 + wv * 16 + col;
            bias_q[q] = (bih[row] + bhh[row]) * sc;
#pragma unroll
            for (int kt = 0; kt < 4; kt++) {
                const float* ph = Whh + (size_t)row * 128 + kt * 32 + quad * 8;
                short8 v;
#pragma unroll
                for (int j = 0; j < 8; j++) v[j] = (short)bf16rne(ph[j] * sc);
                wh[q][kt] = v;
            }
#pragma unroll
            for (int kt = 0; kt < 4; kt++) {
                short8 v = {0, 0, 0, 0, 0, 0, 0, 0};
                if (kt < KX) {
                    const float* px = Wih + (size_t)row * kin + kt * 32 + quad * 8;
#pragma unroll
                    for (int j = 0; j < 8; j++) v[j] = (short)bf16rne(px[j] * sc);
                }
                wx[q][kt] = v;
            }
        }
    }

    unsigned* myflag   = &flags[layer * 32 + grp];
    unsigned* prevflag = &flags[(layer > 0 ? layer - 1 : 0) * 32 + grp];
    unsigned* mycons   = &cons[(layer > 0 ? layer - 1 : 0) * 32 + grp];
    unsigned* nextcons = &cons[layer * 32 + grp];
    char* prodRing = ws + RING_OFF + (size_t)(layer * 32 + grp) * RING_BPG;
    char* consRing = ws + RING_OFF + (size_t)((layer > 0 ? layer - 1 : 0) * 32 + grp) * RING_BPG;

    // precomputed byte offsets (constants through the whole kernel)
    const int ahrd  = col * 264 + quad * 16;                    // A-frag base
    const int hwr   = (quad * 4) * 264 + (wv * 16 + col) * 2;   // h write base
    const int exOff = (tid >> 5) * 264 + (tid & 31) * 8;        // export/stage base
    const int consOff = (tid >> 5) * 256 + (tid & 31) * 8;      // ring qword offset
    const int xgOff = (tid >> 6) * 32768 + b0 * 64 + (tid & 63) * 16;   // xT chunk
    const int xlw0  = (tid >> 6) * 4224 + ((tid >> 2) & 15) * 264 + (tid & 3) * 16;

    ull    xin[8];
    short8 xv = {0, 0, 0, 0, 0, 0, 0, 0};
    unsigned pf = 0, pc = 0;
    float c4[4] = {0.f, 0.f, 0.f, 0.f};
    floatx4 accx[4];               // carried x-part partial sums for step t+1

    __syncthreads();                                   // LDS zeros visible

    // ---- prologue: load+stage chunks 0,1 ---------------------------------
    if (layer > 0) {
        if (tid == 0) { while (ald(prevflag) < 2u) {} }
        __syncthreads();
#pragma unroll
        for (int j = 0; j < 16; j++) {
            ull d = ald8((const ull*)(consRing + (size_t)j * 4096 + consOff));
            *(ull*)(XlB + exOff + j * 4224) = d;
        }
    } else {
#pragma unroll
        for (int c0 = 0; c0 < 2; c0++) {
            short8 v = *(const short8*)(xTB + (size_t)c0 * 262144 + xgOff);
            *(short8*)(XlB + xlw0 + c0 * 33792) = v;
        }
    }
    __syncthreads();

    // ---- prologue: accx for t=0 (x-part from Xl slot 0) ------------------
    {
        short8 ax0[4];
#pragma unroll
        for (int kt = 0; kt < 4; kt++)
            ax0[kt] = *(const short8*)(XlB + ahrd + 0 * 4224 + kt * 64);
#pragma unroll
        for (int q = 0; q < 4; q++) {
            floatx4 a = {bias_q[q], bias_q[q], bias_q[q], bias_q[q]};
            accx[q] = a;
        }
#pragma unroll
        for (int kt = 0; kt < 4; kt++)
#pragma unroll
            for (int q = 0; q < 4; q++)
                accx[q] = __builtin_amdgcn_mfma_f32_16x16x32_bf16(ax0[kt], wx[q][kt], accx[q], 0, 0, 0);
    }

    int c = 0;
    auto step = [&](auto UC) {
        constexpr int u   = UC.value;
        constexpr bool bnd = (u == 0 || u == 8);
        constexpr bool stg = (u == 3 || u == 11);
        constexpr bool ver = (u == 7 || u == 15);
        constexpr int sph = (u < 8) ? 8 : 0;           // slot base for export/stage
        const int cc = c + (u >> 3);
        if (bnd) {
            if (tid == 0) {
                if (layer > 0 && cc <= 111) pf = ald(prevflag);
                if (layer < 3 && cc >= 8)   pc = ald(nextcons);
            }
            if (layer < 3 && cc >= 1) {                // burst chunk cc-1 -> ring
                char* rb = prodRing + (size_t)((cc - 1) & 7) * 32768 + tid * 8;
#pragma unroll
                for (int p = 0; p < 8; p++) {
                    ull hv = *(const ull*)(AhB + exOff + (sph + p) * 4224);
                    ast8((ull*)(rb + p * 4096), hv);
                }
            }
            if (layer > 0 && cc <= 112) {              // load chunk cc+1
                const char* rb2 = consRing + (size_t)((cc + 1) & 7) * 32768 + consOff;
#pragma unroll
                for (int j = 0; j < 8; j++)
                    xin[j] = ald8((const ull*)(rb2 + j * 4096));
            }
            if (layer == 0 && cc <= 112)
                xv = *(const short8*)(xTB + (size_t)(cc + 1) * 262144 + xgOff);
        }
        if (stg) {                                     // stage chunk cc+1 into Xl
            if (layer > 0) {
#pragma unroll
                for (int j = 0; j < 8; j++)
                    *(ull*)(XlB + exOff + (sph + j) * 4224) = xin[j];
            } else {
                *(short8*)(XlB + xlw0 + sph * 4224) = xv;
            }
        }
        // ---- A fragments: h(t-1) and x(t+1) ------------------------------
        short8 ah[4], axn[4];
#pragma unroll
        for (int kt = 0; kt < 4; kt++) {
            ah[kt]  = *(const short8*)(AhB + ahrd + ((u + 15) & 15) * 4224 + kt * 64);
            axn[kt] = *(const short8*)(XlB + ahrd + ((u + 1) & 15) * 4224 + kt * 64);
        }
        // ---- recurrent part: acc = accx + h(t-1)*Wh (4-deep chain per q) --
        floatx4 acc[4];
#pragma unroll
        for (int q = 0; q < 4; q++) acc[q] = accx[q];
#pragma unroll
        for (int kt = 0; kt < 4; kt++)
#pragma unroll
            for (int q = 0; q < 4; q++)
                acc[q] = __builtin_amdgcn_mfma_f32_16x16x32_bf16(ah[kt], wh[q][kt], acc[q], 0, 0, 0);
        // ---- gates(t) INTERLEAVED with x-MFMAs for t+1 --------------------
#pragma unroll
        for (int q = 0; q < 4; q++) {
            floatx4 a = {bias_q[q], bias_q[q], bias_q[q], bias_q[q]};
            accx[q] = a;
        }
#pragma unroll
        for (int r = 0; r < 4; r++) {
            float iv = fastsig(acc[0][r]);
            float fv = fastsig(acc[1][r]);
            float gr = fastsig(acc[2][r]);             // (tanh(g)+1)/2
            float ov = fastsig(acc[3][r]);
            // independent x-MFMA group (kt = r) fills the trans-latency window
#pragma unroll
            for (int q = 0; q < 4; q++)
                accx[q] = __builtin_amdgcn_mfma_f32_16x16x32_bf16(axn[r], wx[q][r], accx[q], 0, 0, 0);
            float gt = 2.f * gr - 1.f;
            float cv = fv * c4[r] + iv * gt;
            c4[r] = cv;
            float rc = fastsig(-2.88539008f * cv);
            float hv = ov * (2.f * rc - 1.f);
            *(unsigned short*)(AhB + hwr + u * 4224 + r * 264) = bf16rne(hv);
        }
        if (stg) {
            __syncthreads();                           // full drain: release point
            if (tid == 0) {
                if (layer < 3 && cc >= 1) ast32(myflag, (unsigned)cc);
                if (layer > 0) ast32(mycons, (unsigned)(cc + 2));
            }
        } else {
            if (ver && tid == 0) {
                if (layer > 0 && cc <= 111) {
                    unsigned tgt = cc + 3;
                    if (pf < tgt) while (ald(prevflag) < tgt) {}
                }
                if (layer < 3 && cc >= 8) {
                    unsigned tgt = cc - 7;
                    if (pc < tgt) while (ald(nextcons) < tgt) {}
                }
            }
            bar_fast();
        }
    };

    for (c = 0; c < 114; c += 2) {
        step(IC<0>{});  step(IC<1>{});  step(IC<2>{});  step(IC<3>{});
        step(IC<4>{});  step(IC<5>{});  step(IC<6>{});  step(IC<7>{});
        step(IC<8>{});  step(IC<9>{});  step(IC<10>{}); step(IC<11>{});
        step(IC<12>{}); step(IC<13>{}); step(IC<14>{}); step(IC<15>{});
    }

    // ---- epilogue: burst chunk 113 (slots 8..15), publish, export hN -----
    if (layer < 3) {
        char* rb = prodRing + (size_t)(113 & 7) * 32768 + tid * 8;
#pragma unroll
        for (int p = 0; p < 8; p++) {
            ull hv = *(const ull*)(AhB + exOff + (8 + p) * 4224);
            ast8((ull*)(rb + p * 4096), hv);
        }
    }
    __syncthreads();                                   // drain ring stores
    if (tid == 0 && layer < 3) ast32(myflag, 114u);
    {
        ull hv = *(const ull*)(AhB + exOff + 15 * 4224);   // h[911]
        *(ull*)(hN8 + ((size_t)layer * 512 + b0 + (tid >> 5)) * 256 + (tid & 31) * 8) = hv;
    }
}

// ---------------------------------------------------------------------------
// heads: hN [4][512][128] bf16 -> opt/tp/sl/lot, each [4][512][4] fp32
__global__ __launch_bounds__(256) void heads(
    const unsigned short* __restrict__ hN,
    const float* __restrict__ Wopt, const float* __restrict__ bopt,
    const float* __restrict__ Wlot, const float* __restrict__ blot,
    const float* __restrict__ Wtp,  const float* __restrict__ btp,
    const float* __restrict__ Wsl,  const float* __restrict__ bsl,
    float* __restrict__ out) {
    int tid = blockIdx.x * 256 + threadIdx.x;
    if (tid >= 4 * 4 * 512) return;
    int b  = tid & 511;
    int l  = (tid >> 9) & 3;
    int hd = tid >> 11;
    const float *W, *bb;
    if      (hd == 0) { W = Wopt; bb = bopt; }
    else if (hd == 1) { W = Wtp;  bb = btp;  }
    else if (hd == 2) { W = Wsl;  bb = bsl;  }
    else              { W = Wlot; bb = blot; }
    const unsigned short* h = hN + ((size_t)l * 512 + b) * 128;
    float z0 = bb[0], z1 = bb[1], z2 = bb[2], z3 = bb[3];
    for (int i = 0; i < 128; i++) {
        float hv = bf16tof(h[i]);
        z0 += hv * W[0 * 128 + i];
        z1 += hv * W[1 * 128 + i];
        z2 += hv * W[2 * 128 + i];
        z3 += hv * W[3 * 128 + i];
    }
    float o0, o1, o2, o3;
    if (hd == 0) {
        float m = fmaxf(fmaxf(z0, z1), fmaxf(z2, z3));
        float e0 = __builtin_amdgcn_exp2f((z0 - m) * 1.44269504f);
        float e1 = __builtin_amdgcn_exp2f((z1 - m) * 1.44269504f);
        float e2 = __builtin_amdgcn_exp2f((z2 - m) * 1.44269504f);
        float e3 = __builtin_amdgcn_exp2f((z3 - m) * 1.44269504f);
        float rs = __builtin_amdgcn_rcpf(e0 + e1 + e2 + e3);
        float p0 = e0 * rs, p1 = e1 * rs, p2 = e2 * rs, p3 = e3 * rs;
        float m2 = fmaxf(fmaxf(p0, p1), fmaxf(p2, p3));
        float f0 = __builtin_amdgcn_exp2f((p0 - m2) * 1.44269504f);
        float f1 = __builtin_amdgcn_exp2f((p1 - m2) * 1.44269504f);
        float f2 = __builtin_amdgcn_exp2f((p2 - m2) * 1.44269504f);
        float f3 = __builtin_amdgcn_exp2f((p3 - m2) * 1.44269504f);
        float rs2 = __builtin_amdgcn_rcpf(f0 + f1 + f2 + f3);
        o0 = f0 * rs2; o1 = f1 * rs2; o2 = f2 * rs2; o3 = f3 * rs2;
    } else {
        o0 = sigm(sigm(z0)); o1 = sigm(sigm(z1));
        o2 = sigm(sigm(z2)); o3 = sigm(sigm(z3));
    }
    float* o = out + (size_t)hd * 8192 + ((size_t)l * 512 + b) * 4;
    o[0] = o0; o[1] = o1; o[2] = o2; o[3] = o3;
}

// ---------------------------------------------------------------------------
extern "C" void kernel_launch(void* const* d_in, const int* in_sizes, int n_in,
                              void* d_out, int out_size, void* d_ws, size_t ws_size,
                              hipStream_t stream) {
    (void)in_sizes; (void)n_in; (void)out_size; (void)ws_size;
    const float* x      = (const float*)d_in[0];
    const float* Wih0   = (const float*)d_in[1];
    const float* Whh0   = (const float*)d_in[2];
    const float* bih0   = (const float*)d_in[3];
    const float* bhh0   = (const float*)d_in[4];
    const float* Wih123 = (const float*)d_in[5];
    const float* Whh123 = (const float*)d_in[6];
    const float* bih123 = (const float*)d_in[7];
    const float* bhh123 = (const float*)d_in[8];
    const float* Wopt = (const float*)d_in[9];
    const float* bopt = (const float*)d_in[10];
    const float* Wlot = (const float*)d_in[11];
    const float* blot = (const float*)d_in[12];
    const float* Wtp  = (const float*)d_in[13];
    const float* btp  = (const float*)d_in[14];
    const float* Wsl  = (const float*)d_in[15];
    const float* bsl  = (const float*)d_in[16];
    char* ws = (char*)d_ws;

    hipMemsetAsync(ws, 0, 1024, stream);               // flags + cons
    xpose<<<(B_ * T_ * 4 + 255) / 256, 256, 0, stream>>>(x, (unsigned short*)(ws + XT_OFF));
    lstm_scan<<<128, 512, 0, stream>>>(Wih0, Whh0, bih0, bhh0,
                                       Wih123, Whh123, bih123, bhh123, ws);
    heads<<<32, 256, 0, stream>>>((const unsigned short*)(ws + HN_OFF),
                                  Wopt, bopt, Wlot, blot, Wtp, btp, Wsl, bsl,
                                  (float*)d_out);
}